// Round 5
// baseline (529.706 us; speedup 1.0000x reference)
//
#include <hip/hip_runtime.h>
#include <hip/hip_bf16.h>

#define HIDDEN 1024
#define INTER 4096
#define NEXP 8
#define T_TOK 2048

typedef short bf16x8 __attribute__((ext_vector_type(8)));
typedef float f32x4 __attribute__((ext_vector_type(4)));

__device__ __forceinline__ unsigned short f2bf(float f) {
    union { float f; unsigned int u; } v; v.f = f;
    unsigned int u = v.u;
    unsigned int r = (u + 0x7FFFu + ((u >> 16) & 1u)) >> 16;
    return (unsigned short)r;
}

// truncating fp32->bf16 pack of 4 floats -> 2 dwords (2x v_perm_b32)
__device__ __forceinline__ uint2 pack4trunc(float4 v) {
    union { float4 f; unsigned short s[8]; } u; u.f = v;
    uint2 r;
    r.x = (unsigned int)u.s[1] | ((unsigned int)u.s[3] << 16);
    r.y = (unsigned int)u.s[5] | ((unsigned int)u.s[7] << 16);
    return r;
}

// R2/R4-proven zero-conflict layout: rows of 64 bf16 (128B), XOR bank swizzle.
__device__ __forceinline__ unsigned int swz(unsigned int row, unsigned int colByte) {
    return (row * 128u + colByte) ^ ((row & 7u) << 4);
}

// raw barrier: NO vmcnt drain (global prefetch stays in flight across it).
__device__ __forceinline__ void block_sync() {
    asm volatile("s_waitcnt lgkmcnt(0)" ::: "memory");
    __builtin_amdgcn_s_barrier();
    asm volatile("" ::: "memory");
}

// ---------------- K1: router (fp32 exact) ----------------
__global__ void router_kernel(const float* __restrict__ x,
                              const float* __restrict__ rw,
                              float* __restrict__ logits_out,
                              int* __restrict__ counts,
                              int* __restrict__ ids,
                              float* __restrict__ wts,
                              int* __restrict__ tsel) {
    int t = blockIdx.x * 4 + (threadIdx.x >> 6);
    int lane = threadIdx.x & 63;
    if (t >= T_TOK) return;
    const float4* xr = (const float4*)(x + (size_t)t * HIDDEN);
    float acc[NEXP];
#pragma unroll
    for (int e = 0; e < NEXP; e++) acc[e] = 0.f;
#pragma unroll
    for (int c = 0; c < 4; c++) {
        float4 xv = xr[lane + c * 64];
#pragma unroll
        for (int e = 0; e < NEXP; e++) {
            float4 wv = ((const float4*)(rw + (size_t)e * HIDDEN))[lane + c * 64];
            acc[e] += xv.x * wv.x + xv.y * wv.y + xv.z * wv.z + xv.w * wv.w;
        }
    }
#pragma unroll
    for (int e = 0; e < NEXP; e++) {
        float v = acc[e];
        for (int off = 32; off >= 1; off >>= 1) v += __shfl_xor(v, off, 64);
        acc[e] = v;
    }
    if (lane == 0) {
        float* lo = logits_out + (size_t)t * NEXP;
        float mx = acc[0];
#pragma unroll
        for (int e = 1; e < NEXP; e++) mx = fmaxf(mx, acc[e]);
        float p[NEXP], s = 0.f;
#pragma unroll
        for (int e = 0; e < NEXP; e++) { p[e] = __expf(acc[e] - mx); s += p[e]; }
        float inv = 1.f / s;
#pragma unroll
        for (int e = 0; e < NEXP; e++) { p[e] *= inv; lo[e] = acc[e]; }
        int i1 = 0;
#pragma unroll
        for (int e = 1; e < NEXP; e++) if (p[e] > p[i1]) i1 = e;
        int i2 = (i1 == 0) ? 1 : 0;
#pragma unroll
        for (int e = 0; e < NEXP; e++) if (e != i1 && e != i2 && p[e] > p[i2]) i2 = e;
        // strict > keeps lowest index on ties (matches jax top_k)
        int s1 = atomicAdd(&counts[i1], 1);
        ids[i1 * T_TOK + s1] = t; wts[i1 * T_TOK + s1] = p[i1];
        int s2 = atomicAdd(&counts[i2], 1);
        ids[i2 * T_TOK + s2] = t; wts[i2 * T_TOK + s2] = p[i2];
        tsel[t * 2]     = i1 * T_TOK + s1;   // pack (expert, slot)
        tsel[t * 2 + 1] = i2 * T_TOK + s2;
    }
}

__global__ void scan_kernel(const int* __restrict__ counts, int* __restrict__ offsets) {
    if (threadIdx.x == 0) {
        int s = 0;
        for (int e = 0; e < NEXP; e++) { offsets[e] = s; s += counts[e]; }
    }
}

// ---------------- K2: fused gate+up grouped GEMM + SwiGLU ----------------
// BM=128 x BN=64 (g and u share A), BK=64, 256 thr (4 waves 2x2, wave 64x32).
// LDS/buf: A 16KB | Bg 8KB | Bu 8KB = 32KB; dbuf 64KB -> 2 blocks/CU.
// 1D grid, XCD-pinned: e = bid&7; within expert mt-fastest (B-stream L2 share).
__global__ __launch_bounds__(256) void gemm_gu(
    const float* __restrict__ x, const float* __restrict__ gw, const float* __restrict__ uw,
    const int* __restrict__ counts, const int* __restrict__ offsets,
    const int* __restrict__ ids, unsigned short* __restrict__ h) {
    const int bid = blockIdx.x;
    const int e = bid & 7;
    const int r = bid >> 3;
    const int mt = r & 15;                        // up to 2048 tokens/expert
    const int nt = r >> 4;                        // 64 tiles of 64 inter cols
    const int cnt = counts[e];
    if (mt * 128 >= cnt) return;
    const int tid = threadIdx.x;
    const int lane = tid & 63, wid = tid >> 6;
    const int wm = wid >> 1, wn = wid & 1;        // 2x2 waves, wave-tile 64x32

    __shared__ __align__(16) char lds[65536];

    const float* gbase = gw + (size_t)e * INTER * HIDDEN;
    const float* ubase = uw + (size_t)e * INTER * HIDDEN;

    // A staging: 128 rows x 64 K fp32 = 2048 float4; 8 per thread
    unsigned int aoff[8], wA[8];
#pragma unroll
    for (int j = 0; j < 8; j++) {
        int fi = j * 256 + tid;
        int row = fi >> 4, c4 = fi & 15;
        int li = mt * 128 + row; if (li >= cnt) li = cnt - 1;
        int gid = ids[e * T_TOK + li];
        aoff[j] = (unsigned int)(gid * HIDDEN + c4 * 4);
        wA[j] = swz(row, c4 * 8);
    }
    // B staging: 64 rows x 64 K fp32 = 1024 float4; 4 per thread (x2: g,u)
    unsigned int boff[4], wB[4];
#pragma unroll
    for (int j = 0; j < 4; j++) {
        int fi = j * 256 + tid;
        int row = fi >> 4, c4 = fi & 15;
        boff[j] = (unsigned int)((nt * 64 + row) * HIDDEN + c4 * 4);
        wB[j] = swz(row, c4 * 8);
    }

    f32x4 accg[4][2], accu[4][2];
#pragma unroll
    for (int mf = 0; mf < 4; mf++)
#pragma unroll
        for (int nf = 0; nf < 2; nf++)
#pragma unroll
            for (int v = 0; v < 4; v++) { accg[mf][nf][v] = 0.f; accu[mf][nf][v] = 0.f; }

    float4 av[8], gv[4], uv[4];
#pragma unroll
    for (int j = 0; j < 8; j++) av[j] = *(const float4*)(x + aoff[j]);
#pragma unroll
    for (int j = 0; j < 4; j++) {
        gv[j] = *(const float4*)(gbase + boff[j]);
        uv[j] = *(const float4*)(ubase + boff[j]);
    }

    for (int kt = 0; kt < 16; kt++) {
        const unsigned int bb = (unsigned int)(kt & 1) << 15;
#pragma unroll
        for (int j = 0; j < 8; j++) *(uint2*)(lds + bb + wA[j]) = pack4trunc(av[j]);
#pragma unroll
        for (int j = 0; j < 4; j++) {
            *(uint2*)(lds + bb + 16384 + wB[j]) = pack4trunc(gv[j]);
            *(uint2*)(lds + bb + 24576 + wB[j]) = pack4trunc(uv[j]);
        }
        if (kt < 15) {                            // prefetch next K-tile
            const int ko = (kt + 1) * 64;
#pragma unroll
            for (int j = 0; j < 8; j++) av[j] = *(const float4*)(x + aoff[j] + ko);
#pragma unroll
            for (int j = 0; j < 4; j++) {
                gv[j] = *(const float4*)(gbase + boff[j] + ko);
                uv[j] = *(const float4*)(ubase + boff[j] + ko);
            }
        }
        block_sync();
#pragma unroll
        for (int ks = 0; ks < 2; ks++) {
            const unsigned int kb = (unsigned int)(ks * 64 + ((lane >> 4) << 4));
            bf16x8 a[4], bg[2], bu[2];
#pragma unroll
            for (int mf = 0; mf < 4; mf++) {
                unsigned int row = (unsigned int)(wm * 64 + mf * 16 + (lane & 15));
                a[mf] = *(const bf16x8*)(lds + bb + swz(row, kb));
            }
#pragma unroll
            for (int nf = 0; nf < 2; nf++) {
                unsigned int row = (unsigned int)(wn * 32 + nf * 16 + (lane & 15));
                bg[nf] = *(const bf16x8*)(lds + bb + 16384 + swz(row, kb));
                bu[nf] = *(const bf16x8*)(lds + bb + 24576 + swz(row, kb));
            }
#pragma unroll
            for (int mf = 0; mf < 4; mf++)
#pragma unroll
                for (int nf = 0; nf < 2; nf++) {
                    accg[mf][nf] = __builtin_amdgcn_mfma_f32_16x16x32_bf16(a[mf], bg[nf], accg[mf][nf], 0, 0, 0);
                    accu[mf][nf] = __builtin_amdgcn_mfma_f32_16x16x32_bf16(a[mf], bu[nf], accu[mf][nf], 0, 0, 0);
                }
        }
        block_sync();                             // readers done before overwrite
    }

    const int hoff = offsets[e];
#pragma unroll
    for (int mf = 0; mf < 4; mf++)
#pragma unroll
        for (int v = 0; v < 4; v++) {
            int il = wm * 64 + mf * 16 + ((lane >> 4) << 2) + v;
            int i = mt * 128 + il;
            if (i < cnt) {
                size_t rowbase = (size_t)(hoff + i) * INTER + nt * 64 + wn * 32 + (lane & 15);
#pragma unroll
                for (int nf = 0; nf < 2; nf++) {
                    float g = accg[mf][nf][v], u = accu[mf][nf][v];
                    float sg = g / (1.f + __expf(-g));
                    h[rowbase + nf * 16] = f2bf(sg * u);
                }
            }
        }
}

// ---------------- K3: down grouped GEMM -> y (no atomics) ----------------
// BM=128 x BN=128, BK=64, 512 thr (8 waves 2x4, wave 64x32), no K-split.
// Writes weighted rows to compact y[4096][1024] fp32. XCD-pinned 1D grid.
// LDS/buf: A 16KB | B 16KB = 32KB; dbuf 64KB -> 2 blocks/CU.
__global__ __launch_bounds__(512) void gemm_down(
    const unsigned short* __restrict__ h, const float* __restrict__ dw,
    const int* __restrict__ counts, const int* __restrict__ offsets,
    const float* __restrict__ wts, float* __restrict__ y) {
    const int bid = blockIdx.x;
    const int e = bid & 7;
    const int r = bid >> 3;
    const int mt = r & 15;                        // up to 2048 tokens/expert
    const int nt = r >> 4;                        // 8 tiles of 128 hidden cols
    const int cnt = counts[e];
    if (mt * 128 >= cnt) return;
    const int tid = threadIdx.x;
    const int lane = tid & 63, wid = tid >> 6;
    const int wm = wid >> 2, wn = wid & 3;        // 2x4 waves, wave-tile 64x32

    __shared__ __align__(16) char lds[65536];

    const int hoff = offsets[e];
    const float* dbase = dw + (size_t)e * HIDDEN * INTER;

    // A staging (h, bf16): 128 rows x 64 K = 1024 16B chunks; 2 per thread
    unsigned int aoff[2], wA[2];
#pragma unroll
    for (int j = 0; j < 2; j++) {
        int fi = j * 512 + tid;
        int row = fi >> 3, c8 = fi & 7;
        int li = mt * 128 + row; if (li >= cnt) li = cnt - 1;
        aoff[j] = (unsigned int)((hoff + li) * INTER + c8 * 8);
        wA[j] = swz(row, c8 * 16);
    }
    // B staging (dw, fp32): 128 rows x 64 K = 2048 float4; 4 per thread
    unsigned int boff[4], wB[4];
#pragma unroll
    for (int j = 0; j < 4; j++) {
        int fi = j * 512 + tid;
        int row = fi >> 4, c4 = fi & 15;
        boff[j] = (unsigned int)((nt * 128 + row) * INTER + c4 * 4);
        wB[j] = swz(row, c4 * 8);
    }

    f32x4 acc[4][2];
#pragma unroll
    for (int mf = 0; mf < 4; mf++)
#pragma unroll
        for (int nf = 0; nf < 2; nf++)
#pragma unroll
            for (int v = 0; v < 4; v++) acc[mf][nf][v] = 0.f;

    int4 av[2]; float4 bv[4];
#pragma unroll
    for (int j = 0; j < 2; j++) av[j] = *(const int4*)(h + aoff[j]);
#pragma unroll
    for (int j = 0; j < 4; j++) bv[j] = *(const float4*)(dbase + boff[j]);

    for (int kt = 0; kt < 64; kt++) {
        const unsigned int bb = (unsigned int)(kt & 1) << 15;
#pragma unroll
        for (int j = 0; j < 2; j++) *(int4*)(lds + bb + wA[j]) = av[j];
#pragma unroll
        for (int j = 0; j < 4; j++) *(uint2*)(lds + bb + 16384 + wB[j]) = pack4trunc(bv[j]);
        if (kt < 63) {
            const int ko = (kt + 1) * 64;
#pragma unroll
            for (int j = 0; j < 2; j++) av[j] = *(const int4*)(h + aoff[j] + ko);
#pragma unroll
            for (int j = 0; j < 4; j++) bv[j] = *(const float4*)(dbase + boff[j] + ko);
        }
        block_sync();
#pragma unroll
        for (int ks = 0; ks < 2; ks++) {
            const unsigned int kb = (unsigned int)(ks * 64 + ((lane >> 4) << 4));
            bf16x8 a[4], bf[2];
#pragma unroll
            for (int mf = 0; mf < 4; mf++) {
                unsigned int row = (unsigned int)(wm * 64 + mf * 16 + (lane & 15));
                a[mf] = *(const bf16x8*)(lds + bb + swz(row, kb));
            }
#pragma unroll
            for (int nf = 0; nf < 2; nf++) {
                unsigned int row = (unsigned int)(wn * 32 + nf * 16 + (lane & 15));
                bf[nf] = *(const bf16x8*)(lds + bb + 16384 + swz(row, kb));
            }
#pragma unroll
            for (int mf = 0; mf < 4; mf++)
#pragma unroll
                for (int nf = 0; nf < 2; nf++)
                    acc[mf][nf] = __builtin_amdgcn_mfma_f32_16x16x32_bf16(a[mf], bf[nf], acc[mf][nf], 0, 0, 0);
        }
        block_sync();
    }

#pragma unroll
    for (int mf = 0; mf < 4; mf++)
#pragma unroll
        for (int v = 0; v < 4; v++) {
            int il = wm * 64 + mf * 16 + ((lane >> 4) << 2) + v;
            int i = mt * 128 + il;
            if (i < cnt) {
                float w = wts[e * T_TOK + i];
                float* yrow = y + (size_t)(hoff + i) * HIDDEN + nt * 128 + wn * 32 + (lane & 15);
#pragma unroll
                for (int nf = 0; nf < 2; nf++)
                    yrow[nf * 16] = w * acc[mf][nf][v];
            }
        }
}

// ---------------- K4: combine (out[t] = y[slot0] + y[slot1]) ----------------
__global__ __launch_bounds__(256) void combine_kernel(
    const float* __restrict__ y, const int* __restrict__ offsets,
    const int* __restrict__ tsel, float* __restrict__ out) {
    const int t = blockIdx.x;
    const int d = threadIdx.x * 4;
    int p0 = tsel[t * 2], p1 = tsel[t * 2 + 1];
    int g0 = offsets[p0 >> 11] + (p0 & (T_TOK - 1));
    int g1 = offsets[p1 >> 11] + (p1 & (T_TOK - 1));
    float4 a = *(const float4*)(y + (size_t)g0 * HIDDEN + d);
    float4 b = *(const float4*)(y + (size_t)g1 * HIDDEN + d);
    float4 o; o.x = a.x + b.x; o.y = a.y + b.y; o.z = a.z + b.z; o.w = a.w + b.w;
    *(float4*)(out + (size_t)t * HIDDEN + d) = o;
}

extern "C" void kernel_launch(void* const* d_in, const int* in_sizes, int n_in,
                              void* d_out, int out_size, void* d_ws, size_t ws_size,
                              hipStream_t stream) {
    const float* x  = (const float*)d_in[0];
    const float* rw = (const float*)d_in[1];
    const float* gw = (const float*)d_in[2];
    const float* uw = (const float*)d_in[3];
    const float* dw = (const float*)d_in[4];
    float* out = (float*)d_out;
    float* logits = out + (size_t)T_TOK * HIDDEN;

    char* ws = (char*)d_ws;
    int*   counts  = (int*)ws;                         // 32 B
    int*   offsets = (int*)(ws + 32);                  // 32 B
    int*   tsel    = (int*)(ws + 1024);                // 16 KB
    int*   ids     = (int*)(ws + 20480);               // 64 KB
    float* wts     = (float*)(ws + 90112);             // 64 KB
    unsigned short* h = (unsigned short*)(ws + 262144);        // 33.55 MB
    float* y       = (float*)(ws + 262144 + 33554432);         // 16.78 MB

    hipMemsetAsync(counts, 0, 8 * sizeof(int), stream);

    router_kernel<<<T_TOK / 4, 256, 0, stream>>>(x, rw, logits, counts, ids, wts, tsel);
    scan_kernel<<<1, 64, 0, stream>>>(counts, offsets);
    gemm_gu<<<8 * 16 * (INTER / 64), 256, 0, stream>>>(x, gw, uw, counts, offsets, ids, h);
    gemm_down<<<8 * 16 * (HIDDEN / 128), 512, 0, stream>>>(h, dw, counts, offsets, wts, y);
    combine_kernel<<<T_TOK, 256, 0, stream>>>(y, offsets, tsel, out);
}

// Round 6
// 293.681 us; speedup vs baseline: 1.8037x; 1.8037x over previous
//
#include <hip/hip_runtime.h>
#include <hip/hip_bf16.h>

#define HIDDEN 1024
#define INTER 4096
#define NEXP 8
#define T_TOK 2048

typedef short bf16x8 __attribute__((ext_vector_type(8)));
typedef float f32x4 __attribute__((ext_vector_type(4)));

__device__ __forceinline__ unsigned short f2bf(float f) {
    union { float f; unsigned int u; } v; v.f = f;
    unsigned int u = v.u;
    unsigned int r = (u + 0x7FFFu + ((u >> 16) & 1u)) >> 16;
    return (unsigned short)r;
}

// truncating fp32->bf16 pack of 4 floats -> 2 dwords (2x v_perm_b32)
__device__ __forceinline__ uint2 pack4trunc(float4 v) {
    union { float4 f; unsigned short s[8]; } u; u.f = v;
    uint2 r;
    r.x = (unsigned int)u.s[1] | ((unsigned int)u.s[3] << 16);
    r.y = (unsigned int)u.s[5] | ((unsigned int)u.s[7] << 16);
    return r;
}

// raw barrier: NO vmcnt drain (global prefetch stays in flight across it).
__device__ __forceinline__ void block_sync() {
    asm volatile("s_waitcnt lgkmcnt(0)" ::: "memory");
    __builtin_amdgcn_s_barrier();
    asm volatile("" ::: "memory");
}

// ---------------- K1: router (fp32 exact) ----------------
__global__ void router_kernel(const float* __restrict__ x,
                              const float* __restrict__ rw,
                              float* __restrict__ logits_out,
                              int* __restrict__ counts,
                              int* __restrict__ ids,
                              float* __restrict__ wts,
                              int* __restrict__ tsel) {
    int t = blockIdx.x * 4 + (threadIdx.x >> 6);
    int lane = threadIdx.x & 63;
    if (t >= T_TOK) return;
    const float4* xr = (const float4*)(x + (size_t)t * HIDDEN);
    float acc[NEXP];
#pragma unroll
    for (int e = 0; e < NEXP; e++) acc[e] = 0.f;
#pragma unroll
    for (int c = 0; c < 4; c++) {
        float4 xv = xr[lane + c * 64];
#pragma unroll
        for (int e = 0; e < NEXP; e++) {
            float4 wv = ((const float4*)(rw + (size_t)e * HIDDEN))[lane + c * 64];
            acc[e] += xv.x * wv.x + xv.y * wv.y + xv.z * wv.z + xv.w * wv.w;
        }
    }
#pragma unroll
    for (int e = 0; e < NEXP; e++) {
        float v = acc[e];
        for (int off = 32; off >= 1; off >>= 1) v += __shfl_xor(v, off, 64);
        acc[e] = v;
    }
    if (lane == 0) {
        float* lo = logits_out + (size_t)t * NEXP;
        float mx = acc[0];
#pragma unroll
        for (int e = 1; e < NEXP; e++) mx = fmaxf(mx, acc[e]);
        float p[NEXP], s = 0.f;
#pragma unroll
        for (int e = 0; e < NEXP; e++) { p[e] = __expf(acc[e] - mx); s += p[e]; }
        float inv = 1.f / s;
#pragma unroll
        for (int e = 0; e < NEXP; e++) { p[e] *= inv; lo[e] = acc[e]; }
        int i1 = 0;
#pragma unroll
        for (int e = 1; e < NEXP; e++) if (p[e] > p[i1]) i1 = e;
        int i2 = (i1 == 0) ? 1 : 0;
#pragma unroll
        for (int e = 0; e < NEXP; e++) if (e != i1 && e != i2 && p[e] > p[i2]) i2 = e;
        // strict > keeps lowest index on ties (matches jax top_k)
        int s1 = atomicAdd(&counts[i1], 1);
        ids[i1 * T_TOK + s1] = t; wts[i1 * T_TOK + s1] = p[i1];
        int s2 = atomicAdd(&counts[i2], 1);
        ids[i2 * T_TOK + s2] = t; wts[i2 * T_TOK + s2] = p[i2];
        tsel[t * 2]     = i1 * T_TOK + s1;   // pack (expert, slot)
        tsel[t * 2 + 1] = i2 * T_TOK + s2;
    }
}

__global__ void scan_kernel(const int* __restrict__ counts, int* __restrict__ offsets) {
    if (threadIdx.x == 0) {
        int s = 0;
        for (int e = 0; e < NEXP; e++) { offsets[e] = s; s += counts[e]; }
    }
}

// ---------------- K2: fused gate+up grouped GEMM + SwiGLU ----------------
// R3-proven high-occupancy config: BM=256 x BN=128, BK=32, 1024 thr (16 waves
// 4x4, wave 64x32), dbuf 2x32KB=64KB -> 2 blocks/CU (32 waves), raw-barrier,
// K-major LDS [kq][row][16B] (on-HW-verified fragment mapping).
__global__ __launch_bounds__(1024) void gemm_gu(
    const float* __restrict__ x, const float* __restrict__ gw, const float* __restrict__ uw,
    const int* __restrict__ counts, const int* __restrict__ offsets,
    const int* __restrict__ ids, unsigned short* __restrict__ h) {
    const int e = blockIdx.z;
    const int cnt = counts[e];
    const int mt = blockIdx.y;
    if (mt * 256 >= cnt) return;
    const int nt = blockIdx.x;                    // 32 tiles of 128 inter
    const int tid = threadIdx.x;
    const int lane = tid & 63, wid = tid >> 6;
    const int wm = wid >> 2, wn = wid & 3;        // 4x4 waves

    __shared__ __align__(16) char lds[65536];

    const float* gbase = gw + (size_t)e * INTER * HIDDEN;
    const float* ubase = uw + (size_t)e * INTER * HIDDEN;

    // A staging: 256 rows x 32 K fp32 = 2048 float4; 2 per thread
    unsigned int aoff[2], wA[2];
#pragma unroll
    for (int j = 0; j < 2; j++) {
        int fi = j * 1024 + tid;
        int row = fi >> 3, c4 = fi & 7;
        int li = mt * 256 + row; if (li >= cnt) li = cnt - 1;
        int gid = ids[e * T_TOK + li];
        aoff[j] = (unsigned int)(gid * HIDDEN + c4 * 4);
        wA[j] = (unsigned int)((c4 >> 1) * 4096 + row * 16 + (c4 & 1) * 8);
    }
    // B staging: 128 rows x 32 K fp32 = 1024 float4; 1 per thread (x2: g,u)
    unsigned int boff, wB;
    {
        int row = tid >> 3, c4 = tid & 7;
        boff = (unsigned int)((nt * 128 + row) * HIDDEN + c4 * 4);
        wB = (unsigned int)((c4 >> 1) * 2048 + row * 16 + (c4 & 1) * 8);
    }

    f32x4 accg[4][2], accu[4][2];
#pragma unroll
    for (int mf = 0; mf < 4; mf++)
#pragma unroll
        for (int nf = 0; nf < 2; nf++)
#pragma unroll
            for (int v = 0; v < 4; v++) { accg[mf][nf][v] = 0.f; accu[mf][nf][v] = 0.f; }

    float4 av[2], gv, uv;
    av[0] = *(const float4*)(x + aoff[0]);
    av[1] = *(const float4*)(x + aoff[1]);
    gv = *(const float4*)(gbase + boff);
    uv = *(const float4*)(ubase + boff);

    for (int kt = 0; kt < 32; kt++) {
        const unsigned int bb = (unsigned int)(kt & 1) << 15;
        *(uint2*)(lds + bb + wA[0]) = pack4trunc(av[0]);
        *(uint2*)(lds + bb + wA[1]) = pack4trunc(av[1]);
        *(uint2*)(lds + bb + 16384 + wB) = pack4trunc(gv);
        *(uint2*)(lds + bb + 24576 + wB) = pack4trunc(uv);
        if (kt < 31) {                            // prefetch next K-tile
            const int ko = (kt + 1) * 32;
            av[0] = *(const float4*)(x + aoff[0] + ko);
            av[1] = *(const float4*)(x + aoff[1] + ko);
            gv = *(const float4*)(gbase + boff + ko);
            uv = *(const float4*)(ubase + boff + ko);
        }
        block_sync();
        const unsigned int kq = (unsigned int)(lane >> 4);
        bf16x8 bg[2], bu[2];
#pragma unroll
        for (int nf = 0; nf < 2; nf++) {
            unsigned int rowb = (unsigned int)(wn * 32 + nf * 16 + (lane & 15));
            bg[nf] = *(const bf16x8*)(lds + bb + 16384 + kq * 2048 + rowb * 16);
            bu[nf] = *(const bf16x8*)(lds + bb + 24576 + kq * 2048 + rowb * 16);
        }
#pragma unroll
        for (int mf = 0; mf < 4; mf++) {
            unsigned int rowa = (unsigned int)(wm * 64 + mf * 16 + (lane & 15));
            bf16x8 a = *(const bf16x8*)(lds + bb + kq * 4096 + rowa * 16);
#pragma unroll
            for (int nf = 0; nf < 2; nf++) {
                accg[mf][nf] = __builtin_amdgcn_mfma_f32_16x16x32_bf16(a, bg[nf], accg[mf][nf], 0, 0, 0);
                accu[mf][nf] = __builtin_amdgcn_mfma_f32_16x16x32_bf16(a, bu[nf], accu[mf][nf], 0, 0, 0);
            }
        }
    }

    const int hoff = offsets[e];
#pragma unroll
    for (int mf = 0; mf < 4; mf++)
#pragma unroll
        for (int v = 0; v < 4; v++) {
            int il = wm * 64 + mf * 16 + ((lane >> 4) << 2) + v;
            int i = mt * 256 + il;
            if (i < cnt) {
                size_t rowbase = (size_t)(hoff + i) * INTER + nt * 128 + wn * 32 + (lane & 15);
#pragma unroll
                for (int nf = 0; nf < 2; nf++) {
                    float g = accg[mf][nf][v], u = accu[mf][nf][v];
                    float sg = g / (1.f + __expf(-g));
                    h[rowbase + nf * 16] = f2bf(sg * u);
                }
            }
        }
}

// ---------------- K3: down grouped GEMM -> y (no atomics) ----------------
// High-occupancy: BM=128 x BN=128, BK=32, ksplit=2, 512 thr (8 waves 2x4,
// wave 64x32), dbuf 2x16KB=32KB -> 4 blocks/CU (32 waves). K-major LDS.
// Writes weighted rows to y[ksp][4096][1024] fp32; combine sums slices.
__global__ __launch_bounds__(512) void gemm_down(
    const unsigned short* __restrict__ h, const float* __restrict__ dw,
    const int* __restrict__ counts, const int* __restrict__ offsets,
    const float* __restrict__ wts, float* __restrict__ y) {
    const int ez = blockIdx.z;                    // e*2 + ksp
    const int e = ez >> 1, ksp = ez & 1;
    const int cnt = counts[e];
    const int mt = blockIdx.y;
    if (mt * 128 >= cnt) return;
    const int nt = blockIdx.x;                    // 8 tiles of 128 hidden
    const int tid = threadIdx.x;
    const int lane = tid & 63, wid = tid >> 6;
    const int wm = wid >> 2, wn = wid & 3;        // 2x4 waves, wave 64x32

    __shared__ __align__(16) char lds[32768];

    const int hoff = offsets[e];
    const float* dbase = dw + (size_t)e * HIDDEN * INTER;

    // A staging (h, bf16): 128 rows x 32 K = 512 16B chunks; 1 per thread
    unsigned int aoff, wAo;
    {
        int row = tid >> 2, c16 = tid & 3;        // c16 = k-octet index
        int li = mt * 128 + row; if (li >= cnt) li = cnt - 1;
        aoff = (unsigned int)((hoff + li) * INTER + ksp * 2048 + c16 * 8);
        wAo = (unsigned int)(c16 * 2048 + row * 16);
    }
    // B staging (dw, fp32): 128 rows x 32 K = 1024 float4; 2 per thread
    unsigned int boff[2], wB[2];
#pragma unroll
    for (int j = 0; j < 2; j++) {
        int fi = j * 512 + tid;
        int row = fi >> 3, c4 = fi & 7;
        boff[j] = (unsigned int)((nt * 128 + row) * INTER + ksp * 2048 + c4 * 4);
        wB[j] = (unsigned int)(8192 + (c4 >> 1) * 2048 + row * 16 + (c4 & 1) * 8);
    }

    f32x4 acc[4][2];
#pragma unroll
    for (int mf = 0; mf < 4; mf++)
#pragma unroll
        for (int nf = 0; nf < 2; nf++)
#pragma unroll
            for (int v = 0; v < 4; v++) acc[mf][nf][v] = 0.f;

    int4 av; float4 bv[2];
    av = *(const int4*)(h + aoff);
    bv[0] = *(const float4*)(dbase + boff[0]);
    bv[1] = *(const float4*)(dbase + boff[1]);

    for (int kt = 0; kt < 64; kt++) {             // 2048 K per split
        const unsigned int bb = (unsigned int)(kt & 1) << 14;
        *(int4*)(lds + bb + wAo) = av;
        *(uint2*)(lds + bb + wB[0]) = pack4trunc(bv[0]);
        *(uint2*)(lds + bb + wB[1]) = pack4trunc(bv[1]);
        if (kt < 63) {
            const int ko = (kt + 1) * 32;
            av = *(const int4*)(h + aoff + ko);
            bv[0] = *(const float4*)(dbase + boff[0] + ko);
            bv[1] = *(const float4*)(dbase + boff[1] + ko);
        }
        block_sync();
        const unsigned int kq = (unsigned int)(lane >> 4);
        bf16x8 bf[2];
#pragma unroll
        for (int nf = 0; nf < 2; nf++) {
            unsigned int rowb = (unsigned int)(wn * 32 + nf * 16 + (lane & 15));
            bf[nf] = *(const bf16x8*)(lds + bb + 8192 + kq * 2048 + rowb * 16);
        }
#pragma unroll
        for (int mf = 0; mf < 4; mf++) {
            unsigned int rowa = (unsigned int)(wm * 64 + mf * 16 + (lane & 15));
            bf16x8 a = *(const bf16x8*)(lds + bb + kq * 2048 + rowa * 16);
#pragma unroll
            for (int nf = 0; nf < 2; nf++)
                acc[mf][nf] = __builtin_amdgcn_mfma_f32_16x16x32_bf16(a, bf[nf], acc[mf][nf], 0, 0, 0);
        }
    }

#pragma unroll
    for (int mf = 0; mf < 4; mf++)
#pragma unroll
        for (int v = 0; v < 4; v++) {
            int il = wm * 64 + mf * 16 + ((lane >> 4) << 2) + v;
            int i = mt * 128 + il;
            if (i < cnt) {
                float w = wts[e * T_TOK + i];
                float* yrow = y + ((size_t)ksp * 4096 + hoff + i) * HIDDEN
                                + nt * 128 + wn * 32 + (lane & 15);
#pragma unroll
                for (int nf = 0; nf < 2; nf++)
                    yrow[nf * 16] = w * acc[mf][nf][v];
            }
        }
}

// -------- K4: combine (out[t] = sum over 2 experts x 2 ksplits) --------
__global__ __launch_bounds__(256) void combine_kernel(
    const float* __restrict__ y, const int* __restrict__ offsets,
    const int* __restrict__ tsel, float* __restrict__ out) {
    const int t = blockIdx.x;
    const int d = threadIdx.x * 4;
    int p0 = tsel[t * 2], p1 = tsel[t * 2 + 1];
    size_t g0 = (size_t)(offsets[p0 >> 11] + (p0 & (T_TOK - 1)));
    size_t g1 = (size_t)(offsets[p1 >> 11] + (p1 & (T_TOK - 1)));
    float4 a0 = *(const float4*)(y + g0 * HIDDEN + d);
    float4 a1 = *(const float4*)(y + (4096 + g0) * HIDDEN + d);
    float4 b0 = *(const float4*)(y + g1 * HIDDEN + d);
    float4 b1 = *(const float4*)(y + (4096 + g1) * HIDDEN + d);
    float4 o;
    o.x = (a0.x + a1.x) + (b0.x + b1.x);
    o.y = (a0.y + a1.y) + (b0.y + b1.y);
    o.z = (a0.z + a1.z) + (b0.z + b1.z);
    o.w = (a0.w + a1.w) + (b0.w + b1.w);
    *(float4*)(out + (size_t)t * HIDDEN + d) = o;
}

extern "C" void kernel_launch(void* const* d_in, const int* in_sizes, int n_in,
                              void* d_out, int out_size, void* d_ws, size_t ws_size,
                              hipStream_t stream) {
    const float* x  = (const float*)d_in[0];
    const float* rw = (const float*)d_in[1];
    const float* gw = (const float*)d_in[2];
    const float* uw = (const float*)d_in[3];
    const float* dw = (const float*)d_in[4];
    float* out = (float*)d_out;
    float* logits = out + (size_t)T_TOK * HIDDEN;

    char* ws = (char*)d_ws;
    int*   counts  = (int*)ws;                         // 32 B
    int*   offsets = (int*)(ws + 32);                  // 32 B
    int*   tsel    = (int*)(ws + 1024);                // 16 KB
    int*   ids     = (int*)(ws + 20480);               // 64 KB
    float* wts     = (float*)(ws + 90112);             // 64 KB
    unsigned short* h = (unsigned short*)(ws + 262144);        // 33.55 MB
    float* y       = (float*)(ws + 262144 + 33554432);         // 2 x 16.78 MB

    hipMemsetAsync(counts, 0, 8 * sizeof(int), stream);

    router_kernel<<<T_TOK / 4, 256, 0, stream>>>(x, rw, logits, counts, ids, wts, tsel);
    scan_kernel<<<1, 64, 0, stream>>>(counts, offsets);
    gemm_gu<<<dim3(INTER / 128, 8, NEXP), 1024, 0, stream>>>(x, gw, uw, counts, offsets, ids, h);
    gemm_down<<<dim3(HIDDEN / 128, 16, NEXP * 2), 512, 0, stream>>>(h, dw, counts, offsets, wts, y);
    combine_kernel<<<T_TOK, 256, 0, stream>>>(y, offsets, tsel, out);
}